// Round 3
// baseline (591.108 us; speedup 1.0000x reference)
//
#include <hip/hip_runtime.h>
#include <hip/hip_bf16.h>
#include <stdint.h>

// ---------------- problem dims (fixed by setup_inputs) ----------------
#define S_TOK   2048   // tokens (B*S)
#define DMODEL  2048   // D
#define HEXP    512    // H per expert
#define NEXP    32     // E
#define HSH     1024   // shared hidden
#define NPAIR   (S_TOK * 4)   // 8192 (token,expert) pairs, top_k=4
#define MAXTILES 96           // sum ceil(cnt_e/128) <= 8192/128 + 32 = 96

// meta layout (ints)
#define META_NT  0
#define META_TE  1
#define META_TP0 (1 + MAXTILES)
#define META_TM  (1 + 2 * MAXTILES)
#define META_SIZE (1 + 3 * MAXTILES)

#define LDP 40   // LDS row length in shorts (80B rows, 16B-aligned; A-reads ~2-way = free)

typedef short  s16x8 __attribute__((ext_vector_type(8)));
typedef __bf16 b16x8 __attribute__((ext_vector_type(8)));
typedef float  f32x4 __attribute__((ext_vector_type(4)));

__device__ __forceinline__ f32x4 mfma16x16x32(s16x8 a, s16x8 b, f32x4 c) {
    return __builtin_amdgcn_mfma_f32_16x16x32_bf16(
        __builtin_bit_cast(b16x8, a), __builtin_bit_cast(b16x8, b), c, 0, 0, 0);
}

__device__ __forceinline__ unsigned short f2bf(float f) {
    union { float f; unsigned int u; } v; v.f = f;
    unsigned int u = v.u;
    return (unsigned short)((u + 0x7FFFu + ((u >> 16) & 1u)) >> 16);  // RNE
}

// ---------------- router: logits, sigmoid, biased top-4, coef softmax ----------------
__global__ __launch_bounds__(256)
void router_kernel(const float* __restrict__ x, const float* __restrict__ gate_w,
                   const float* __restrict__ expert_bias,
                   const float* __restrict__ coef_w, const float* __restrict__ coef_b,
                   int* __restrict__ inds, float* __restrict__ scores,
                   float* __restrict__ coefo)
{
    const int t = blockIdx.x;
    const int tid = threadIdx.x;
    const int lane = tid & 63;
    const int wave = tid >> 6;
    const float* xr = x + (size_t)t * DMODEL;

    float xv[32];
#pragma unroll
    for (int j = 0; j < 32; ++j) xv[j] = xr[lane + 64 * j];

    __shared__ float s_logits[NEXP];
    __shared__ float s_coef[2];

    for (int i = 0; i < 8; ++i) {
        const int e = wave * 8 + i;
        const float* wr = gate_w + (size_t)e * DMODEL;
        float p = 0.f;
#pragma unroll
        for (int j = 0; j < 32; ++j) p += xv[j] * wr[lane + 64 * j];
#pragma unroll
        for (int o = 32; o > 0; o >>= 1) p += __shfl_xor(p, o);
        if (lane == 0) s_logits[e] = p;
    }
    if (wave == 0) {
        for (int c = 0; c < 2; ++c) {
            const float* wr = coef_w + (size_t)c * DMODEL;
            float p = 0.f;
#pragma unroll
            for (int j = 0; j < 32; ++j) p += xv[j] * wr[lane + 64 * j];
#pragma unroll
            for (int o = 32; o > 0; o >>= 1) p += __shfl_xor(p, o);
            if (lane == 0) s_coef[c] = p;
        }
    }
    __syncthreads();
    if (tid == 0) {
        float routing[NEXP], biased[NEXP];
        for (int e = 0; e < NEXP; ++e) {
            const float r = 1.f / (1.f + expf(-s_logits[e]));
            routing[e] = r;
            biased[e] = r + expert_bias[e];
        }
        int sel[4]; float sc[4]; float ssum = 0.f;
        for (int k = 0; k < 4; ++k) {
            int best = 0; float bv = -1e30f;
            for (int e = 0; e < NEXP; ++e)
                if (biased[e] > bv) { bv = biased[e]; best = e; }  // strict > = lax.top_k tie rule
            sel[k] = best; sc[k] = routing[best]; ssum += sc[k];
            biased[best] = -1e30f;
        }
        const float inv = 1.f / (ssum + 1e-20f);
        for (int k = 0; k < 4; ++k) {
            inds[t * 4 + k] = sel[k];
            scores[t * 4 + k] = sc[k] * inv;
        }
        const float l0 = s_coef[0] + coef_b[0];
        const float l1 = s_coef[1] + coef_b[1];
        const float m = fmaxf(l0, l1);
        const float e0 = expf(l0 - m), e1 = expf(l1 - m);
        coefo[t * 2 + 0] = e0 / (e0 + e1);
        coefo[t * 2 + 1] = e1 / (e0 + e1);
    }
}

// ---------------- x: f32 -> bf16 ----------------
__global__ __launch_bounds__(256)
void xcast_kernel(const float* __restrict__ x, unsigned short* __restrict__ xb)
{
    const int i = (blockIdx.x * 256 + threadIdx.x) * 4;
    const float4 v = *reinterpret_cast<const float4*>(x + i);
    ushort4 o;
    o.x = f2bf(v.x); o.y = f2bf(v.y); o.z = f2bf(v.z); o.w = f2bf(v.w);
    *reinterpret_cast<ushort4*>(xb + i) = o;
}

// ---------------- grouping: per-expert pair lists + tile table ----------------
__global__ __launch_bounds__(1024)
void group_kernel(const int* __restrict__ inds, const float* __restrict__ scores,
                  int* __restrict__ meta, int* __restrict__ pair_token,
                  float* __restrict__ pair_score)
{
    __shared__ int cnt[NEXP];
    __shared__ int off_s[NEXP];
    __shared__ int cur[NEXP];
    const int tid = threadIdx.x;
    if (tid < NEXP) cnt[tid] = 0;
    __syncthreads();
    for (int i = tid; i < NPAIR; i += 1024) atomicAdd(&cnt[inds[i]], 1);
    __syncthreads();
    if (tid == 0) {
        int run = 0, nt = 0;
        for (int e = 0; e < NEXP; ++e) {
            off_s[e] = run;
            const int c = cnt[e];
            for (int m0 = 0; m0 < c; m0 += 128) {
                meta[META_TE + nt] = e;
                meta[META_TP0 + nt] = run + m0;
                meta[META_TM + nt] = (c - m0 < 128) ? (c - m0) : 128;
                ++nt;
            }
            run += c;
        }
        meta[META_NT] = nt;
    }
    __syncthreads();
    if (tid < NEXP) cur[tid] = off_s[tid];
    __syncthreads();
    for (int i = tid; i < NPAIR; i += 1024) {
        const int e = inds[i];
        const int pos = atomicAdd(&cur[e], 1);
        pair_token[pos] = i >> 2;
        pair_score[pos] = scores[i];
    }
}

// ---------------- gate+up GEMM, fused SwiGLU, bf16 act out ----------------
// BM=128, BK=32, dual-B (g,u) 64 cols each. 4 waves 2x2; wave tile 64m x 32n per B.
// 2-phase, one barrier/iter: issue loads(t+1) -> compute buf[t] -> convert+ds_write
// buf[t^1] (vmcnt waits land here, after the MFMA window) -> barrier.
// Staging regs: A 2xuint4 (8) + B 16 floats = 24 VGPR  -- proven no-spill budget (r1).
template <bool GATHER>
__global__ __launch_bounds__(256, 2)
void gateup_kernel(const unsigned short* __restrict__ xb,
                   const float* __restrict__ Bg_all, const float* __restrict__ Bu_all,
                   unsigned short* __restrict__ act,
                   const int* __restrict__ meta, const int* __restrict__ pair_token,
                   const int NB)   // act/N stride: 512 (experts) or 1024 (shared)
{
    constexpr int NT = DMODEL / 32;   // K = 2048
    __shared__ unsigned short Al[2][128][LDP];
    __shared__ unsigned short Bl[2][128][LDP];   // rows: [0..63]=g cols, [64..127]=u cols

    const int tid = threadIdx.x;
    int p0, mval;
    const float *Bg, *Bu;
    if constexpr (GATHER) {
        const int tt = blockIdx.y;
        if (tt >= meta[META_NT]) return;
        const int e = meta[META_TE + tt];
        p0 = meta[META_TP0 + tt];
        mval = meta[META_TM + tt];
        const size_t eoff = (size_t)e * DMODEL * NB;
        Bg = Bg_all + eoff;
        Bu = Bu_all + eoff;
    } else {
        p0 = blockIdx.y * 128;
        mval = 128;
        Bg = Bg_all;
        Bu = Bu_all;
    }
    const int n0 = blockIdx.x * 64;

    // A staging: thread -> (row arow, 16-short half aoff); 16 shorts = 2 uint4
    const int arow = tid >> 1;
    const int aoff = (tid & 1) * 16;
    int tok;
    if constexpr (GATHER) {
        int p = p0 + arow; if (p > NPAIR - 1) p = NPAIR - 1;
        tok = pair_token[p];
    } else {
        tok = p0 + arow;
    }
    const unsigned short* asrc = xb + (size_t)tok * DMODEL + aoff;

    // B staging: thread -> (col bcol, 8 k-values at bkb); coalesced across threads
    const int bcol = tid & 63;
    const int bkb = (tid >> 6) * 8;
    const float* gsrc = Bg + (size_t)bkb * NB + (n0 + bcol);
    const float* usrc = Bu + (size_t)bkb * NB + (n0 + bcol);

    uint4 areg[2];
    float greg[8], ureg[8];

    auto load_regs = [&](int k0) {
        areg[0] = *reinterpret_cast<const uint4*>(asrc + k0);
        areg[1] = *reinterpret_cast<const uint4*>(asrc + k0 + 8);
#pragma unroll
        for (int j = 0; j < 8; ++j) {
            greg[j] = gsrc[(size_t)(k0 + j) * NB];
            ureg[j] = usrc[(size_t)(k0 + j) * NB];
        }
    };
    auto write_lds = [&](int buf) {
        *reinterpret_cast<uint4*>(&Al[buf][arow][aoff])     = areg[0];
        *reinterpret_cast<uint4*>(&Al[buf][arow][aoff + 8]) = areg[1];
        union { unsigned short us[8]; uint4 v; } g_, u_;
#pragma unroll
        for (int j = 0; j < 8; ++j) { g_.us[j] = f2bf(greg[j]); u_.us[j] = f2bf(ureg[j]); }
        *reinterpret_cast<uint4*>(&Bl[buf][bcol][bkb])      = g_.v;
        *reinterpret_cast<uint4*>(&Bl[buf][64 + bcol][bkb]) = u_.v;
    };

    const int lane = tid & 63;
    const int wave = tid >> 6;
    const int wm = wave >> 1, wn = wave & 1;
    const int fr = lane & 15, fq = lane >> 4;

    const f32x4 zero4 = {0.f, 0.f, 0.f, 0.f};
    f32x4 hacc[4][2], uacc[4][2];
#pragma unroll
    for (int m = 0; m < 4; ++m)
#pragma unroll
        for (int n = 0; n < 2; ++n) { hacc[m][n] = zero4; uacc[m][n] = zero4; }

    auto compute = [&](int buf) {
        const int ko = fq * 8;
        s16x8 af[4], bg[2], bu[2];
#pragma unroll
        for (int m = 0; m < 4; ++m)
            af[m] = *reinterpret_cast<const s16x8*>(&Al[buf][wm * 64 + m * 16 + fr][ko]);
#pragma unroll
        for (int n = 0; n < 2; ++n) {
            bg[n] = *reinterpret_cast<const s16x8*>(&Bl[buf][wn * 32 + n * 16 + fr][ko]);
            bu[n] = *reinterpret_cast<const s16x8*>(&Bl[buf][64 + wn * 32 + n * 16 + fr][ko]);
        }
#pragma unroll
        for (int m = 0; m < 4; ++m)
#pragma unroll
            for (int n = 0; n < 2; ++n) {
                hacc[m][n] = mfma16x16x32(af[m], bg[n], hacc[m][n]);
                uacc[m][n] = mfma16x16x32(af[m], bu[n], uacc[m][n]);
            }
    };

    // prologue
    load_regs(0);
    write_lds(0);
    __syncthreads();
    for (int t = 0; t < NT; ++t) {
        const int cur = t & 1;
        if (t + 1 < NT) load_regs((t + 1) * 32);   // VMEM in flight under compute
        compute(cur);
        if (t + 1 < NT) write_lds(cur ^ 1);        // vmcnt waits land here
        __syncthreads();
    }

    // epilogue: act = silu(h)*u -> bf16. C/D frag: col=lane&15, row=fq*4+r
#pragma unroll
    for (int m = 0; m < 4; ++m)
#pragma unroll
        for (int n = 0; n < 2; ++n) {
            const int col = n0 + wn * 32 + n * 16 + fr;
#pragma unroll
            for (int r = 0; r < 4; ++r) {
                const int rt = wm * 64 + m * 16 + fq * 4 + r;
                if (rt < mval) {
                    const float hv = hacc[m][n][r];
                    const float a = hv / (1.f + __expf(-hv)) * uacc[m][n][r];
                    act[(size_t)(p0 + rt) * NB + col] = f2bf(a);
                }
            }
        }
}

// ---------------- down GEMM: BM=128, BN=128, BK=32 ----------------
// EXPERT=true : A = act rows (pair-major), epilogue atomicAdd(out, v*score)
// EXPERT=false: A = shared act, epilogue out = out*c0 + v*c1 (final combine)
template <bool EXPERT>
__global__ __launch_bounds__(256, 2)
void down_kernel(const unsigned short* __restrict__ act,
                 const float* __restrict__ Bd_all,
                 float* __restrict__ out,
                 const int* __restrict__ meta, const int* __restrict__ pair_token,
                 const float* __restrict__ pair_score, const float* __restrict__ coef,
                 const int KA)   // 512 or 1024; A row stride == KA; B row stride = DMODEL
{
    const int NT = KA / 32;
    __shared__ unsigned short Al[2][128][LDP];
    __shared__ unsigned short Bl[2][128][LDP];

    const int tid = threadIdx.x;
    int p0, mval;
    const float* Bd;
    if constexpr (EXPERT) {
        const int tt = blockIdx.y;
        if (tt >= meta[META_NT]) return;
        const int e = meta[META_TE + tt];
        p0 = meta[META_TP0 + tt];
        mval = meta[META_TM + tt];
        Bd = Bd_all + (size_t)e * KA * DMODEL;
    } else {
        p0 = blockIdx.y * 128;
        mval = 128;
        Bd = Bd_all;
    }
    const int n0 = blockIdx.x * 128;

    const int arow = tid >> 1;
    const int aoff = (tid & 1) * 16;
    int ar = p0 + arow;
    if constexpr (EXPERT) { if (ar > NPAIR - 1) ar = NPAIR - 1; }
    const unsigned short* asrc = act + (size_t)ar * KA + aoff;

    // B staging: col = tid&127, 16 k-values at bkb
    const int bcol = tid & 127;
    const int bkb = (tid >> 7) * 16;
    const float* bsrc = Bd + (size_t)bkb * DMODEL + (n0 + bcol);

    uint4 areg[2];
    float breg[16];

    auto load_regs = [&](int k0) {
        areg[0] = *reinterpret_cast<const uint4*>(asrc + k0);
        areg[1] = *reinterpret_cast<const uint4*>(asrc + k0 + 8);
#pragma unroll
        for (int j = 0; j < 16; ++j)
            breg[j] = bsrc[(size_t)(k0 + j) * DMODEL];
    };
    auto write_lds = [&](int buf) {
        *reinterpret_cast<uint4*>(&Al[buf][arow][aoff])     = areg[0];
        *reinterpret_cast<uint4*>(&Al[buf][arow][aoff + 8]) = areg[1];
        union { unsigned short us[16]; uint4 v[2]; } b_;
#pragma unroll
        for (int j = 0; j < 16; ++j) b_.us[j] = f2bf(breg[j]);
        *reinterpret_cast<uint4*>(&Bl[buf][bcol][bkb])     = b_.v[0];
        *reinterpret_cast<uint4*>(&Bl[buf][bcol][bkb + 8]) = b_.v[1];
    };

    const int lane = tid & 63;
    const int wave = tid >> 6;
    const int wm = wave >> 1, wn = wave & 1;
    const int fr = lane & 15, fq = lane >> 4;

    const f32x4 zero4 = {0.f, 0.f, 0.f, 0.f};
    f32x4 acc[4][4];
#pragma unroll
    for (int m = 0; m < 4; ++m)
#pragma unroll
        for (int n = 0; n < 4; ++n) acc[m][n] = zero4;

    auto compute = [&](int buf) {
        const int ko = fq * 8;
        s16x8 af[4], bf[4];
#pragma unroll
        for (int m = 0; m < 4; ++m)
            af[m] = *reinterpret_cast<const s16x8*>(&Al[buf][wm * 64 + m * 16 + fr][ko]);
#pragma unroll
        for (int n = 0; n < 4; ++n)
            bf[n] = *reinterpret_cast<const s16x8*>(&Bl[buf][wn * 64 + n * 16 + fr][ko]);
#pragma unroll
        for (int m = 0; m < 4; ++m)
#pragma unroll
            for (int n = 0; n < 4; ++n)
                acc[m][n] = mfma16x16x32(af[m], bf[n], acc[m][n]);
    };

    load_regs(0);
    write_lds(0);
    __syncthreads();
    for (int t = 0; t < NT; ++t) {
        const int cur = t & 1;
        if (t + 1 < NT) load_regs((t + 1) * 32);
        compute(cur);
        if (t + 1 < NT) write_lds(cur ^ 1);
        __syncthreads();
    }

#pragma unroll
    for (int m = 0; m < 4; ++m)
#pragma unroll
        for (int n = 0; n < 4; ++n) {
            const int col = n0 + wn * 64 + n * 16 + fr;
#pragma unroll
            for (int r = 0; r < 4; ++r) {
                const int rt = wm * 64 + m * 16 + fq * 4 + r;
                if (rt < mval) {
                    if constexpr (EXPERT) {
                        const int p = p0 + rt;
                        const int t2 = pair_token[p];
                        const float s = pair_score[p];
                        atomicAdd(&out[(size_t)t2 * DMODEL + col], acc[m][n][r] * s);
                    } else {
                        const int row = p0 + rt;
                        const float c0 = coef[row * 2 + 0];
                        const float c1 = coef[row * 2 + 1];
                        const size_t idx = (size_t)row * DMODEL + col;
                        out[idx] = out[idx] * c0 + acc[m][n][r] * c1;
                    }
                }
            }
        }
}

// ---------------- launch ----------------
extern "C" void kernel_launch(void* const* d_in, const int* in_sizes, int n_in,
                              void* d_out, int out_size, void* d_ws, size_t ws_size,
                              hipStream_t stream)
{
    const float* x           = (const float*)d_in[0];
    const float* gate_w      = (const float*)d_in[1];
    const float* expert_bias = (const float*)d_in[2];
    const float* wg          = (const float*)d_in[3];
    const float* wu          = (const float*)d_in[4];
    const float* wd          = (const float*)d_in[5];
    const float* sg          = (const float*)d_in[6];
    const float* su          = (const float*)d_in[7];
    const float* sd          = (const float*)d_in[8];
    const float* coef_w      = (const float*)d_in[9];
    const float* coef_b      = (const float*)d_in[10];
    float* out = (float*)d_out;

    char* ws = (char*)d_ws;
    size_t off = 0;
    auto take = [&](size_t bytes) {
        char* p = ws + off;
        off = (off + bytes + 255) & ~(size_t)255;
        return p;
    };
    int*   inds     = (int*)  take((size_t)S_TOK * 4 * sizeof(int));
    float* scores   = (float*)take((size_t)S_TOK * 4 * sizeof(float));
    float* coefp    = (float*)take((size_t)S_TOK * 2 * sizeof(float));
    int*   meta     = (int*)  take((size_t)META_SIZE * sizeof(int));
    int*   pair_tok = (int*)  take((size_t)NPAIR * sizeof(int));
    float* pair_sc  = (float*)take((size_t)NPAIR * sizeof(float));
    unsigned short* xb    = (unsigned short*)take((size_t)S_TOK * DMODEL * 2);
    unsigned short* act   = (unsigned short*)take((size_t)NPAIR * HEXP * 2);
    unsigned short* shact = (unsigned short*)take((size_t)S_TOK * HSH * 2);
    (void)ws_size; (void)in_sizes; (void)n_in; (void)out_size;

    // out doubles as the expert-y accumulator; zero it each call
    hipMemsetAsync(d_out, 0, (size_t)S_TOK * DMODEL * sizeof(float), stream);

    router_kernel<<<S_TOK, 256, 0, stream>>>(x, gate_w, expert_bias, coef_w, coef_b,
                                             inds, scores, coefp);
    xcast_kernel<<<(S_TOK * DMODEL / 4) / 256, 256, 0, stream>>>(x, xb);
    group_kernel<<<1, 1024, 0, stream>>>(inds, scores, meta, pair_tok, pair_sc);

    // expert gate+up (+SwiGLU): 8 n-tiles x up-to-96 m-tiles (tile table)
    gateup_kernel<true><<<dim3(HEXP / 64, MAXTILES), 256, 0, stream>>>(
        xb, wg, wu, act, meta, pair_tok, HEXP);
    // shared gate+up: N=1024, M=2048
    gateup_kernel<false><<<dim3(HSH / 64, S_TOK / 128), 256, 0, stream>>>(
        xb, sg, su, shact, nullptr, nullptr, HSH);
    // expert down: N=2048 (BN=128), K=512; scaled atomic accumulate into out
    down_kernel<true><<<dim3(DMODEL / 128, MAXTILES), 256, 0, stream>>>(
        act, wd, out, meta, pair_tok, pair_sc, nullptr, HEXP);
    // shared down + final 2-way coef mix (reads accumulated expert y in-place)
    down_kernel<false><<<dim3(DMODEL / 128, S_TOK / 128), 256, 0, stream>>>(
        shact, sd, out, nullptr, nullptr, nullptr, coefp, HSH);
}

// Round 4
// 455.924 us; speedup vs baseline: 1.2965x; 1.2965x over previous
//
#include <hip/hip_runtime.h>
#include <hip/hip_bf16.h>
#include <stdint.h>

// ---------------- problem dims (fixed by setup_inputs) ----------------
#define S_TOK   2048   // tokens (B*S)
#define DMODEL  2048   // D
#define HEXP    512    // H per expert
#define NEXP    32     // E
#define HSH     1024   // shared hidden
#define NPAIR   (S_TOK * 4)   // 8192 (token,expert) pairs, top_k=4
#define MAXTILES 96           // sum ceil(cnt_e/128) <= 8192/128 + 32 = 96

// meta layout (ints)
#define META_NT  0
#define META_TE  1
#define META_TP0 (1 + MAXTILES)
#define META_TM  (1 + 2 * MAXTILES)
#define META_SIZE (1 + 3 * MAXTILES)

#define LDP 40   // LDS row length in shorts (80B rows, 16B-aligned)

typedef short  s16x8 __attribute__((ext_vector_type(8)));
typedef __bf16 b16x8 __attribute__((ext_vector_type(8)));
typedef float  f32x4 __attribute__((ext_vector_type(4)));

__device__ __forceinline__ f32x4 mfma16x16x32(s16x8 a, s16x8 b, f32x4 c) {
    return __builtin_amdgcn_mfma_f32_16x16x32_bf16(
        __builtin_bit_cast(b16x8, a), __builtin_bit_cast(b16x8, b), c, 0, 0, 0);
}

__device__ __forceinline__ unsigned short f2bf(float f) {
    union { float f; unsigned int u; } v; v.f = f;
    unsigned int u = v.u;
    return (unsigned short)((u + 0x7FFFu + ((u >> 16) & 1u)) >> 16);  // RNE
}

__device__ __forceinline__ unsigned int pack2bf(float lo, float hi) {
    return (unsigned int)f2bf(lo) | ((unsigned int)f2bf(hi) << 16);
}

// ---------------- router: logits, sigmoid, biased top-4, coef softmax ----------------
__global__ __launch_bounds__(256)
void router_kernel(const float* __restrict__ x, const float* __restrict__ gate_w,
                   const float* __restrict__ expert_bias,
                   const float* __restrict__ coef_w, const float* __restrict__ coef_b,
                   int* __restrict__ inds, float* __restrict__ scores,
                   float* __restrict__ coefo)
{
    const int t = blockIdx.x;
    const int tid = threadIdx.x;
    const int lane = tid & 63;
    const int wave = tid >> 6;
    const float* xr = x + (size_t)t * DMODEL;

    float xv[32];
#pragma unroll
    for (int j = 0; j < 32; ++j) xv[j] = xr[lane + 64 * j];

    __shared__ float s_logits[NEXP];
    __shared__ float s_coef[2];

    for (int i = 0; i < 8; ++i) {
        const int e = wave * 8 + i;
        const float* wr = gate_w + (size_t)e * DMODEL;
        float p = 0.f;
#pragma unroll
        for (int j = 0; j < 32; ++j) p += xv[j] * wr[lane + 64 * j];
#pragma unroll
        for (int o = 32; o > 0; o >>= 1) p += __shfl_xor(p, o);
        if (lane == 0) s_logits[e] = p;
    }
    if (wave == 0) {
        for (int c = 0; c < 2; ++c) {
            const float* wr = coef_w + (size_t)c * DMODEL;
            float p = 0.f;
#pragma unroll
            for (int j = 0; j < 32; ++j) p += xv[j] * wr[lane + 64 * j];
#pragma unroll
            for (int o = 32; o > 0; o >>= 1) p += __shfl_xor(p, o);
            if (lane == 0) s_coef[c] = p;
        }
    }
    __syncthreads();
    if (tid == 0) {
        float routing[NEXP], biased[NEXP];
        for (int e = 0; e < NEXP; ++e) {
            const float r = 1.f / (1.f + expf(-s_logits[e]));
            routing[e] = r;
            biased[e] = r + expert_bias[e];
        }
        int sel[4]; float sc[4]; float ssum = 0.f;
        for (int k = 0; k < 4; ++k) {
            int best = 0; float bv = -1e30f;
            for (int e = 0; e < NEXP; ++e)
                if (biased[e] > bv) { bv = biased[e]; best = e; }  // strict > = lax.top_k tie rule
            sel[k] = best; sc[k] = routing[best]; ssum += sc[k];
            biased[best] = -1e30f;
        }
        const float inv = 1.f / (ssum + 1e-20f);
        for (int k = 0; k < 4; ++k) {
            inds[t * 4 + k] = sel[k];
            scores[t * 4 + k] = sc[k] * inv;
        }
        const float l0 = s_coef[0] + coef_b[0];
        const float l1 = s_coef[1] + coef_b[1];
        const float m = fmaxf(l0, l1);
        const float e0 = expf(l0 - m), e1 = expf(l1 - m);
        coefo[t * 2 + 0] = e0 / (e0 + e1);
        coefo[t * 2 + 1] = e1 / (e0 + e1);
    }
}

// ---------------- x: f32 -> bf16 ----------------
__global__ __launch_bounds__(256)
void xcast_kernel(const float* __restrict__ x, unsigned short* __restrict__ xb)
{
    const int i = (blockIdx.x * 256 + threadIdx.x) * 4;
    const float4 v = *reinterpret_cast<const float4*>(x + i);
    ushort4 o;
    o.x = f2bf(v.x); o.y = f2bf(v.y); o.z = f2bf(v.z); o.w = f2bf(v.w);
    *reinterpret_cast<ushort4*>(xb + i) = o;
}

// ---------------- grouping: per-expert pair lists + tile table ----------------
__global__ __launch_bounds__(1024)
void group_kernel(const int* __restrict__ inds, const float* __restrict__ scores,
                  int* __restrict__ meta, int* __restrict__ pair_token,
                  float* __restrict__ pair_score)
{
    __shared__ int cnt[NEXP];
    __shared__ int off_s[NEXP];
    __shared__ int cur[NEXP];
    const int tid = threadIdx.x;
    if (tid < NEXP) cnt[tid] = 0;
    __syncthreads();
    for (int i = tid; i < NPAIR; i += 1024) atomicAdd(&cnt[inds[i]], 1);
    __syncthreads();
    if (tid == 0) {
        int run = 0, nt = 0;
        for (int e = 0; e < NEXP; ++e) {
            off_s[e] = run;
            const int c = cnt[e];
            for (int m0 = 0; m0 < c; m0 += 128) {
                meta[META_TE + nt] = e;
                meta[META_TP0 + nt] = run + m0;
                meta[META_TM + nt] = (c - m0 < 128) ? (c - m0) : 128;
                ++nt;
            }
            run += c;
        }
        meta[META_NT] = nt;
    }
    __syncthreads();
    if (tid < NEXP) cur[tid] = off_s[tid];
    __syncthreads();
    for (int i = tid; i < NPAIR; i += 1024) {
        const int e = inds[i];
        const int pos = atomicAdd(&cur[e], 1);
        pair_token[pos] = i >> 2;
        pair_score[pos] = scores[i];
    }
}

// ---------------- gate+up GEMM, fused SwiGLU, bf16 act out ----------------
// BM=128, BK=32, dual-B (g,u) 64 cols each. 4 waves 2x2; wave tile 64m x 32n per B.
// Double-buffered LDS, ONE barrier per K-step, manually unrolled x2 so every
// buffer index is a compile-time constant (runtime buf indexing / compiler
// re-pipelining caused the r2/r3 scratch spills). #pragma unroll 1 pins it.
template <bool GATHER>
__global__ __launch_bounds__(256, 2)
void gateup_kernel(const unsigned short* __restrict__ xb,
                   const float* __restrict__ Bg_all, const float* __restrict__ Bu_all,
                   unsigned short* __restrict__ act,
                   const int* __restrict__ meta, const int* __restrict__ pair_token,
                   const int NB)   // act/N stride: 512 (experts) or 1024 (shared)
{
    constexpr int NT = DMODEL / 32;   // 64 K-steps (even)
    __shared__ unsigned short Al[2][128][LDP];
    __shared__ unsigned short Bl[2][128][LDP];   // rows: [0..63]=g cols, [64..127]=u cols

    const int tid = threadIdx.x;
    int p0, mval;
    const float *Bg, *Bu;
    if constexpr (GATHER) {
        const int tt = blockIdx.y;
        if (tt >= meta[META_NT]) return;
        const int e = meta[META_TE + tt];
        p0 = meta[META_TP0 + tt];
        mval = meta[META_TM + tt];
        const size_t eoff = (size_t)e * DMODEL * NB;
        Bg = Bg_all + eoff;
        Bu = Bu_all + eoff;
    } else {
        p0 = blockIdx.y * 128;
        mval = 128;
        Bg = Bg_all;
        Bu = Bu_all;
    }
    const int n0 = blockIdx.x * 64;

    // A staging: thread -> (row arow, 16-short half aoff)
    const int arow = tid >> 1;
    const int aoff = (tid & 1) * 16;
    int tok;
    if constexpr (GATHER) {
        int p = p0 + arow; if (p > NPAIR - 1) p = NPAIR - 1;
        tok = pair_token[p];
    } else {
        tok = p0 + arow;
    }
    const unsigned short* asrc = xb + (size_t)tok * DMODEL + aoff;

    // B staging: thread -> (col bcol, 8 k-values at bkb); coalesced across lanes
    const int bcol = tid & 63;
    const int bkb = (tid >> 6) * 8;
    const float* gsrc = Bg + (size_t)bkb * NB + (n0 + bcol);
    const float* usrc = Bu + (size_t)bkb * NB + (n0 + bcol);

    uint4 areg0, areg1;
    float greg[8], ureg[8];

    auto load_regs = [&](int k0) {
        areg0 = *reinterpret_cast<const uint4*>(asrc + k0);
        areg1 = *reinterpret_cast<const uint4*>(asrc + k0 + 8);
#pragma unroll
        for (int j = 0; j < 8; ++j) {
            greg[j] = gsrc[(size_t)(k0 + j) * NB];
            ureg[j] = usrc[(size_t)(k0 + j) * NB];
        }
    };
    // buf is always a literal at call sites -> constant-folds after inlining
    auto write_lds = [&](int buf) {
        *reinterpret_cast<uint4*>(&Al[buf][arow][aoff])     = areg0;
        *reinterpret_cast<uint4*>(&Al[buf][arow][aoff + 8]) = areg1;
        uint4 g_, u_;
        g_.x = pack2bf(greg[0], greg[1]); g_.y = pack2bf(greg[2], greg[3]);
        g_.z = pack2bf(greg[4], greg[5]); g_.w = pack2bf(greg[6], greg[7]);
        u_.x = pack2bf(ureg[0], ureg[1]); u_.y = pack2bf(ureg[2], ureg[3]);
        u_.z = pack2bf(ureg[4], ureg[5]); u_.w = pack2bf(ureg[6], ureg[7]);
        *reinterpret_cast<uint4*>(&Bl[buf][bcol][bkb])      = g_;
        *reinterpret_cast<uint4*>(&Bl[buf][64 + bcol][bkb]) = u_;
    };

    const int lane = tid & 63;
    const int wave = tid >> 6;
    const int wm = wave >> 1, wn = wave & 1;
    const int fr = lane & 15, fq = lane >> 4;

    const f32x4 zero4 = {0.f, 0.f, 0.f, 0.f};
    f32x4 hacc[4][2], uacc[4][2];
#pragma unroll
    for (int m = 0; m < 4; ++m)
#pragma unroll
        for (int n = 0; n < 2; ++n) { hacc[m][n] = zero4; uacc[m][n] = zero4; }

    auto compute = [&](int buf) {
        const int ko = fq * 8;
        s16x8 af[4], bg[2], bu[2];
#pragma unroll
        for (int m = 0; m < 4; ++m)
            af[m] = *reinterpret_cast<const s16x8*>(&Al[buf][wm * 64 + m * 16 + fr][ko]);
#pragma unroll
        for (int n = 0; n < 2; ++n) {
            bg[n] = *reinterpret_cast<const s16x8*>(&Bl[buf][wn * 32 + n * 16 + fr][ko]);
            bu[n] = *reinterpret_cast<const s16x8*>(&Bl[buf][64 + wn * 32 + n * 16 + fr][ko]);
        }
#pragma unroll
        for (int m = 0; m < 4; ++m)
#pragma unroll
            for (int n = 0; n < 2; ++n) {
                hacc[m][n] = mfma16x16x32(af[m], bg[n], hacc[m][n]);
                uacc[m][n] = mfma16x16x32(af[m], bu[n], uacc[m][n]);
            }
    };

    // prologue: tile 0 -> buf0
    load_regs(0);
    write_lds(0);
    __syncthreads();
#pragma unroll 1
    for (int t = 0; t < NT; t += 2) {
        // tile t in buf0; stage tile t+1 -> buf1
        if (t + 1 < NT) load_regs((t + 1) * 32);
        compute(0);
        if (t + 1 < NT) write_lds(1);      // vmcnt wait lands here, after MFMA window
        __syncthreads();
        // tile t+1 in buf1; stage tile t+2 -> buf0
        if (t + 2 < NT) load_regs((t + 2) * 32);
        compute(1);
        if (t + 2 < NT) write_lds(0);
        __syncthreads();
    }

    // epilogue: act = silu(h)*u -> bf16. C/D frag: col=lane&15, row=fq*4+r
#pragma unroll
    for (int m = 0; m < 4; ++m)
#pragma unroll
        for (int n = 0; n < 2; ++n) {
            const int col = n0 + wn * 32 + n * 16 + fr;
#pragma unroll
            for (int r = 0; r < 4; ++r) {
                const int rt = wm * 64 + m * 16 + fq * 4 + r;
                if (rt < mval) {
                    const float hv = hacc[m][n][r];
                    const float a = hv / (1.f + __expf(-hv)) * uacc[m][n][r];
                    act[(size_t)(p0 + rt) * NB + col] = f2bf(a);
                }
            }
        }
}

// ---------------- down GEMM: BM=128, BN=128, BK=32 ----------------
// Same pipeline discipline as gateup (manual x2 unroll, compile-time buf).
// EXPERT=true : A = act rows (pair-major), epilogue atomicAdd(out, v*score)
// EXPERT=false: A = shared act, epilogue out = out*c0 + v*c1 (final combine)
template <bool EXPERT>
__global__ __launch_bounds__(256, 2)
void down_kernel(const unsigned short* __restrict__ act,
                 const float* __restrict__ Bd_all,
                 float* __restrict__ out,
                 const int* __restrict__ meta, const int* __restrict__ pair_token,
                 const float* __restrict__ pair_score, const float* __restrict__ coef,
                 const int KA)   // 512 or 1024; A row stride == KA; B row stride = DMODEL
{
    const int NT = KA / 32;   // 16 or 32 (even)
    __shared__ unsigned short Al[2][128][LDP];
    __shared__ unsigned short Bl[2][128][LDP];

    const int tid = threadIdx.x;
    int p0, mval;
    const float* Bd;
    if constexpr (EXPERT) {
        const int tt = blockIdx.y;
        if (tt >= meta[META_NT]) return;
        const int e = meta[META_TE + tt];
        p0 = meta[META_TP0 + tt];
        mval = meta[META_TM + tt];
        Bd = Bd_all + (size_t)e * KA * DMODEL;
    } else {
        p0 = blockIdx.y * 128;
        mval = 128;
        Bd = Bd_all;
    }
    const int n0 = blockIdx.x * 128;

    const int arow = tid >> 1;
    const int aoff = (tid & 1) * 16;
    int ar = p0 + arow;
    if constexpr (EXPERT) { if (ar > NPAIR - 1) ar = NPAIR - 1; }
    const unsigned short* asrc = act + (size_t)ar * KA + aoff;

    // B staging: col = tid&127, 16 k-values at bkb
    const int bcol = tid & 127;
    const int bkb = (tid >> 7) * 16;
    const float* bsrc = Bd + (size_t)bkb * DMODEL + (n0 + bcol);

    uint4 areg0, areg1;
    float breg[16];

    auto load_regs = [&](int k0) {
        areg0 = *reinterpret_cast<const uint4*>(asrc + k0);
        areg1 = *reinterpret_cast<const uint4*>(asrc + k0 + 8);
#pragma unroll
        for (int j = 0; j < 16; ++j)
            breg[j] = bsrc[(size_t)(k0 + j) * DMODEL];
    };
    auto write_lds = [&](int buf) {
        *reinterpret_cast<uint4*>(&Al[buf][arow][aoff])     = areg0;
        *reinterpret_cast<uint4*>(&Al[buf][arow][aoff + 8]) = areg1;
        uint4 b0, b1;
        b0.x = pack2bf(breg[0],  breg[1]);  b0.y = pack2bf(breg[2],  breg[3]);
        b0.z = pack2bf(breg[4],  breg[5]);  b0.w = pack2bf(breg[6],  breg[7]);
        b1.x = pack2bf(breg[8],  breg[9]);  b1.y = pack2bf(breg[10], breg[11]);
        b1.z = pack2bf(breg[12], breg[13]); b1.w = pack2bf(breg[14], breg[15]);
        *reinterpret_cast<uint4*>(&Bl[buf][bcol][bkb])     = b0;
        *reinterpret_cast<uint4*>(&Bl[buf][bcol][bkb + 8]) = b1;
    };

    const int lane = tid & 63;
    const int wave = tid >> 6;
    const int wm = wave >> 1, wn = wave & 1;
    const int fr = lane & 15, fq = lane >> 4;

    const f32x4 zero4 = {0.f, 0.f, 0.f, 0.f};
    f32x4 acc[4][4];
#pragma unroll
    for (int m = 0; m < 4; ++m)
#pragma unroll
        for (int n = 0; n < 4; ++n) acc[m][n] = zero4;

    auto compute = [&](int buf) {
        const int ko = fq * 8;
        s16x8 af[4], bf[4];
#pragma unroll
        for (int m = 0; m < 4; ++m)
            af[m] = *reinterpret_cast<const s16x8*>(&Al[buf][wm * 64 + m * 16 + fr][ko]);
#pragma unroll
        for (int n = 0; n < 4; ++n)
            bf[n] = *reinterpret_cast<const s16x8*>(&Bl[buf][wn * 64 + n * 16 + fr][ko]);
#pragma unroll
        for (int m = 0; m < 4; ++m)
#pragma unroll
            for (int n = 0; n < 4; ++n)
                acc[m][n] = mfma16x16x32(af[m], bf[n], acc[m][n]);
    };

    load_regs(0);
    write_lds(0);
    __syncthreads();
#pragma unroll 1
    for (int t = 0; t < NT; t += 2) {
        if (t + 1 < NT) load_regs((t + 1) * 32);
        compute(0);
        if (t + 1 < NT) write_lds(1);
        __syncthreads();
        if (t + 2 < NT) load_regs((t + 2) * 32);
        compute(1);
        if (t + 2 < NT) write_lds(0);
        __syncthreads();
    }

#pragma unroll
    for (int m = 0; m < 4; ++m)
#pragma unroll
        for (int n = 0; n < 4; ++n) {
            const int col = n0 + wn * 64 + n * 16 + fr;
#pragma unroll
            for (int r = 0; r < 4; ++r) {
                const int rt = wm * 64 + m * 16 + fq * 4 + r;
                if (rt < mval) {
                    if constexpr (EXPERT) {
                        const int p = p0 + rt;
                        const int t2 = pair_token[p];
                        const float s = pair_score[p];
                        atomicAdd(&out[(size_t)t2 * DMODEL + col], acc[m][n][r] * s);
                    } else {
                        const int row = p0 + rt;
                        const float c0 = coef[row * 2 + 0];
                        const float c1 = coef[row * 2 + 1];
                        const size_t idx = (size_t)row * DMODEL + col;
                        out[idx] = out[idx] * c0 + acc[m][n][r] * c1;
                    }
                }
            }
        }
}

// ---------------- launch ----------------
extern "C" void kernel_launch(void* const* d_in, const int* in_sizes, int n_in,
                              void* d_out, int out_size, void* d_ws, size_t ws_size,
                              hipStream_t stream)
{
    const float* x           = (const float*)d_in[0];
    const float* gate_w      = (const float*)d_in[1];
    const float* expert_bias = (const float*)d_in[2];
    const float* wg          = (const float*)d_in[3];
    const float* wu          = (const float*)d_in[4];
    const float* wd          = (const float*)d_in[5];
    const float* sg          = (const float*)d_in[6];
    const float* su          = (const float*)d_in[7];
    const float* sd          = (const float*)d_in[8];
    const float* coef_w      = (const float*)d_in[9];
    const float* coef_b      = (const float*)d_in[10];
    float* out = (float*)d_out;

    char* ws = (char*)d_ws;
    size_t off = 0;
    auto take = [&](size_t bytes) {
        char* p = ws + off;
        off = (off + bytes + 255) & ~(size_t)255;
        return p;
    };
    int*   inds     = (int*)  take((size_t)S_TOK * 4 * sizeof(int));
    float* scores   = (float*)take((size_t)S_TOK * 4 * sizeof(float));
    float* coefp    = (float*)take((size_t)S_TOK * 2 * sizeof(float));
    int*   meta     = (int*)  take((size_t)META_SIZE * sizeof(int));
    int*   pair_tok = (int*)  take((size_t)NPAIR * sizeof(int));
    float* pair_sc  = (float*)take((size_t)NPAIR * sizeof(float));
    unsigned short* xb    = (unsigned short*)take((size_t)S_TOK * DMODEL * 2);
    unsigned short* act   = (unsigned short*)take((size_t)NPAIR * HEXP * 2);
    unsigned short* shact = (unsigned short*)take((size_t)S_TOK * HSH * 2);
    (void)ws_size; (void)in_sizes; (void)n_in; (void)out_size;

    // out doubles as the expert-y accumulator; zero it each call
    hipMemsetAsync(d_out, 0, (size_t)S_TOK * DMODEL * sizeof(float), stream);

    router_kernel<<<S_TOK, 256, 0, stream>>>(x, gate_w, expert_bias, coef_w, coef_b,
                                             inds, scores, coefp);
    xcast_kernel<<<(S_TOK * DMODEL / 4) / 256, 256, 0, stream>>>(x, xb);
    group_kernel<<<1, 1024, 0, stream>>>(inds, scores, meta, pair_tok, pair_sc);

    // expert gate+up (+SwiGLU): 8 n-tiles x up-to-96 m-tiles (tile table)
    gateup_kernel<true><<<dim3(HEXP / 64, MAXTILES), 256, 0, stream>>>(
        xb, wg, wu, act, meta, pair_tok, HEXP);
    // shared gate+up: N=1024, M=2048
    gateup_kernel<false><<<dim3(HSH / 64, S_TOK / 128), 256, 0, stream>>>(
        xb, sg, su, shact, nullptr, nullptr, HSH);
    // expert down: N=2048 (BN=128), K=512; scaled atomic accumulate into out
    down_kernel<true><<<dim3(DMODEL / 128, MAXTILES), 256, 0, stream>>>(
        act, wd, out, meta, pair_tok, pair_sc, nullptr, HEXP);
    // shared down + final 2-way coef mix (reads accumulated expert y in-place)
    down_kernel<false><<<dim3(DMODEL / 128, S_TOK / 128), 256, 0, stream>>>(
        shact, sd, out, nullptr, nullptr, nullptr, coefp, HSH);
}

// Round 5
// 378.922 us; speedup vs baseline: 1.5600x; 1.2032x over previous
//
#include <hip/hip_runtime.h>
#include <hip/hip_bf16.h>
#include <stdint.h>

// ---------------- problem dims (fixed by setup_inputs) ----------------
#define S_TOK   2048   // tokens (B*S)
#define DMODEL  2048   // D
#define HEXP    512    // H per expert
#define NEXP    32     // E
#define HSH     1024   // shared hidden
#define NPAIR   (S_TOK * 4)   // 8192 (token,expert) pairs, top_k=4
#define MAXTILES 96           // sum ceil(cnt_e/128) <= 8192/128 + 32 = 96

// meta layout (ints)
#define META_NT  0
#define META_TE  1
#define META_TP0 (1 + MAXTILES)
#define META_TM  (1 + 2 * MAXTILES)
#define META_SIZE (1 + 3 * MAXTILES)

#define LDP 72   // LDS row length in shorts for BK=64 (144B rows; frag reads 2-way = free)

typedef short  s16x8 __attribute__((ext_vector_type(8)));
typedef __bf16 b16x8 __attribute__((ext_vector_type(8)));
typedef float  f32x4 __attribute__((ext_vector_type(4)));

__device__ __forceinline__ f32x4 mfma16x16x32(s16x8 a, s16x8 b, f32x4 c) {
    return __builtin_amdgcn_mfma_f32_16x16x32_bf16(
        __builtin_bit_cast(b16x8, a), __builtin_bit_cast(b16x8, b), c, 0, 0, 0);
}

__device__ __forceinline__ unsigned short f2bf(float f) {
    union { float f; unsigned int u; } v; v.f = f;
    unsigned int u = v.u;
    return (unsigned short)((u + 0x7FFFu + ((u >> 16) & 1u)) >> 16);  // RNE
}

__device__ __forceinline__ unsigned int pack2bf(float lo, float hi) {
    return (unsigned int)f2bf(lo) | ((unsigned int)f2bf(hi) << 16);
}

// ---------------- router: logits, sigmoid, biased top-4, coef softmax ----------------
__global__ __launch_bounds__(256)
void router_kernel(const float* __restrict__ x, const float* __restrict__ gate_w,
                   const float* __restrict__ expert_bias,
                   const float* __restrict__ coef_w, const float* __restrict__ coef_b,
                   int* __restrict__ inds, float* __restrict__ scores,
                   float* __restrict__ coefo)
{
    const int t = blockIdx.x;
    const int tid = threadIdx.x;
    const int lane = tid & 63;
    const int wave = tid >> 6;
    const float* xr = x + (size_t)t * DMODEL;

    float xv[32];
#pragma unroll
    for (int j = 0; j < 32; ++j) xv[j] = xr[lane + 64 * j];

    __shared__ float s_logits[NEXP];
    __shared__ float s_coef[2];

    for (int i = 0; i < 8; ++i) {
        const int e = wave * 8 + i;
        const float* wr = gate_w + (size_t)e * DMODEL;
        float p = 0.f;
#pragma unroll
        for (int j = 0; j < 32; ++j) p += xv[j] * wr[lane + 64 * j];
#pragma unroll
        for (int o = 32; o > 0; o >>= 1) p += __shfl_xor(p, o);
        if (lane == 0) s_logits[e] = p;
    }
    if (wave == 0) {
        for (int c = 0; c < 2; ++c) {
            const float* wr = coef_w + (size_t)c * DMODEL;
            float p = 0.f;
#pragma unroll
            for (int j = 0; j < 32; ++j) p += xv[j] * wr[lane + 64 * j];
#pragma unroll
            for (int o = 32; o > 0; o >>= 1) p += __shfl_xor(p, o);
            if (lane == 0) s_coef[c] = p;
        }
    }
    __syncthreads();
    if (tid == 0) {
        float routing[NEXP], biased[NEXP];
        for (int e = 0; e < NEXP; ++e) {
            const float r = 1.f / (1.f + expf(-s_logits[e]));
            routing[e] = r;
            biased[e] = r + expert_bias[e];
        }
        int sel[4]; float sc[4]; float ssum = 0.f;
        for (int k = 0; k < 4; ++k) {
            int best = 0; float bv = -1e30f;
            for (int e = 0; e < NEXP; ++e)
                if (biased[e] > bv) { bv = biased[e]; best = e; }  // strict > = lax.top_k tie rule
            sel[k] = best; sc[k] = routing[best]; ssum += sc[k];
            biased[best] = -1e30f;
        }
        const float inv = 1.f / (ssum + 1e-20f);
        for (int k = 0; k < 4; ++k) {
            inds[t * 4 + k] = sel[k];
            scores[t * 4 + k] = sc[k] * inv;
        }
        const float l0 = s_coef[0] + coef_b[0];
        const float l1 = s_coef[1] + coef_b[1];
        const float m = fmaxf(l0, l1);
        const float e0 = expf(l0 - m), e1 = expf(l1 - m);
        coefo[t * 2 + 0] = e0 / (e0 + e1);
        coefo[t * 2 + 1] = e1 / (e0 + e1);
    }
}

// ---------------- x: f32 -> bf16 ----------------
__global__ __launch_bounds__(256)
void xcast_kernel(const float* __restrict__ x, unsigned short* __restrict__ xb)
{
    const int i = (blockIdx.x * 256 + threadIdx.x) * 4;
    const float4 v = *reinterpret_cast<const float4*>(x + i);
    ushort4 o;
    o.x = f2bf(v.x); o.y = f2bf(v.y); o.z = f2bf(v.z); o.w = f2bf(v.w);
    *reinterpret_cast<ushort4*>(xb + i) = o;
}

// ---------------- grouping: per-expert pair lists + tile table ----------------
__global__ __launch_bounds__(1024)
void group_kernel(const int* __restrict__ inds, const float* __restrict__ scores,
                  int* __restrict__ meta, int* __restrict__ pair_token,
                  float* __restrict__ pair_score)
{
    __shared__ int cnt[NEXP];
    __shared__ int off_s[NEXP];
    __shared__ int cur[NEXP];
    const int tid = threadIdx.x;
    if (tid < NEXP) cnt[tid] = 0;
    __syncthreads();
    for (int i = tid; i < NPAIR; i += 1024) atomicAdd(&cnt[inds[i]], 1);
    __syncthreads();
    if (tid == 0) {
        int run = 0, nt = 0;
        for (int e = 0; e < NEXP; ++e) {
            off_s[e] = run;
            const int c = cnt[e];
            for (int m0 = 0; m0 < c; m0 += 128) {
                meta[META_TE + nt] = e;
                meta[META_TP0 + nt] = run + m0;
                meta[META_TM + nt] = (c - m0 < 128) ? (c - m0) : 128;
                ++nt;
            }
            run += c;
        }
        meta[META_NT] = nt;
    }
    __syncthreads();
    if (tid < NEXP) cur[tid] = off_s[tid];
    __syncthreads();
    for (int i = tid; i < NPAIR; i += 1024) {
        const int e = inds[i];
        const int pos = atomicAdd(&cur[e], 1);
        pair_token[pos] = i >> 2;
        pair_score[pos] = scores[i];
    }
}

// ---------------- gate+up GEMM, fused SwiGLU, bf16 act out ----------------
// BM=128, BK=64, dual-B (g,u) 64 cols each. 512 threads = 8 waves as 2m x 4n;
// wave tile 64m x 16n per B-matrix. Double-buffered LDS, ONE barrier per K-step,
// manual x2 unroll (compile-time buf indices; r2/r3 spill lesson), unroll-1 outer.
// Staging: A 2xuint4 + B 16 floats = 24 VGPR (proven no-spill budget).
template <bool GATHER>
__global__ __launch_bounds__(512, 4)
void gateup_kernel(const unsigned short* __restrict__ xb,
                   const float* __restrict__ Bg_all, const float* __restrict__ Bu_all,
                   unsigned short* __restrict__ act,
                   const int* __restrict__ meta, const int* __restrict__ pair_token,
                   const int NB)   // act/N stride: 512 (experts) or 1024 (shared)
{
    constexpr int NT = DMODEL / 64;   // 32 K-steps (even)
    __shared__ unsigned short Al[2][128][LDP];
    __shared__ unsigned short Bl[2][128][LDP];   // rows: [0..63]=g cols, [64..127]=u cols

    const int tid = threadIdx.x;
    int p0, mval;
    const float *Bg, *Bu;
    if constexpr (GATHER) {
        const int tt = blockIdx.y;
        if (tt >= meta[META_NT]) return;
        const int e = meta[META_TE + tt];
        p0 = meta[META_TP0 + tt];
        mval = meta[META_TM + tt];
        const size_t eoff = (size_t)e * DMODEL * NB;
        Bg = Bg_all + eoff;
        Bu = Bu_all + eoff;
    } else {
        p0 = blockIdx.y * 128;
        mval = 128;
        Bg = Bg_all;
        Bu = Bu_all;
    }
    const int n0 = blockIdx.x * 64;

    // A staging: thread -> (row arow, 16-short quarter aoff)
    const int arow = tid >> 2;
    const int aoff = (tid & 3) * 16;
    int tok;
    if constexpr (GATHER) {
        int p = p0 + arow; if (p > NPAIR - 1) p = NPAIR - 1;
        tok = pair_token[p];
    } else {
        tok = p0 + arow;
    }
    const unsigned short* asrc = xb + (size_t)tok * DMODEL + aoff;

    // B staging: thread -> (col bcol, 8 k-values at kg*8); coalesced across lanes
    const int bcol = tid & 63;
    const int bkb = (tid >> 6) * 8;   // 8 k-groups x 8 k = 64
    const float* gsrc = Bg + (size_t)bkb * NB + (n0 + bcol);
    const float* usrc = Bu + (size_t)bkb * NB + (n0 + bcol);

    uint4 areg0, areg1;
    float greg[8], ureg[8];

    auto load_regs = [&](int k0) {
        areg0 = *reinterpret_cast<const uint4*>(asrc + k0);
        areg1 = *reinterpret_cast<const uint4*>(asrc + k0 + 8);
#pragma unroll
        for (int j = 0; j < 8; ++j) {
            greg[j] = gsrc[(size_t)(k0 + j) * NB];
            ureg[j] = usrc[(size_t)(k0 + j) * NB];
        }
    };
    // buf is always a literal at call sites -> constant-folds after inlining
    auto write_lds = [&](int buf) {
        *reinterpret_cast<uint4*>(&Al[buf][arow][aoff])     = areg0;
        *reinterpret_cast<uint4*>(&Al[buf][arow][aoff + 8]) = areg1;
        uint4 g_, u_;
        g_.x = pack2bf(greg[0], greg[1]); g_.y = pack2bf(greg[2], greg[3]);
        g_.z = pack2bf(greg[4], greg[5]); g_.w = pack2bf(greg[6], greg[7]);
        u_.x = pack2bf(ureg[0], ureg[1]); u_.y = pack2bf(ureg[2], ureg[3]);
        u_.z = pack2bf(ureg[4], ureg[5]); u_.w = pack2bf(ureg[6], ureg[7]);
        *reinterpret_cast<uint4*>(&Bl[buf][bcol][bkb])      = g_;
        *reinterpret_cast<uint4*>(&Bl[buf][64 + bcol][bkb]) = u_;
    };

    const int lane = tid & 63;
    const int wave = tid >> 6;
    const int wm = wave >> 2, wn = wave & 3;   // 2m x 4n
    const int fr = lane & 15, fq = lane >> 4;

    const f32x4 zero4 = {0.f, 0.f, 0.f, 0.f};
    f32x4 hacc[4], uacc[4];
#pragma unroll
    for (int m = 0; m < 4; ++m) { hacc[m] = zero4; uacc[m] = zero4; }

    auto compute = [&](int buf) {
#pragma unroll
        for (int kk = 0; kk < 2; ++kk) {
            const int ko = kk * 32 + fq * 8;
            s16x8 af[4], bg, bu;
#pragma unroll
            for (int m = 0; m < 4; ++m)
                af[m] = *reinterpret_cast<const s16x8*>(&Al[buf][wm * 64 + m * 16 + fr][ko]);
            bg = *reinterpret_cast<const s16x8*>(&Bl[buf][wn * 16 + fr][ko]);
            bu = *reinterpret_cast<const s16x8*>(&Bl[buf][64 + wn * 16 + fr][ko]);
#pragma unroll
            for (int m = 0; m < 4; ++m) {
                hacc[m] = mfma16x16x32(af[m], bg, hacc[m]);
                uacc[m] = mfma16x16x32(af[m], bu, uacc[m]);
            }
        }
    };

    // prologue: tile 0 -> buf0
    load_regs(0);
    write_lds(0);
    __syncthreads();
#pragma unroll 1
    for (int t = 0; t < NT; t += 2) {
        if (t + 1 < NT) load_regs((t + 1) * 64);
        compute(0);
        if (t + 1 < NT) write_lds(1);      // vmcnt wait lands here, after MFMA window
        __syncthreads();
        if (t + 2 < NT) load_regs((t + 2) * 64);
        compute(1);
        if (t + 2 < NT) write_lds(0);
        __syncthreads();
    }

    // epilogue: act = silu(h)*u -> bf16. C/D frag: col=lane&15, row=fq*4+r
#pragma unroll
    for (int m = 0; m < 4; ++m) {
        const int col = n0 + wn * 16 + fr;
#pragma unroll
        for (int r = 0; r < 4; ++r) {
            const int rt = wm * 64 + m * 16 + fq * 4 + r;
            if (rt < mval) {
                const float hv = hacc[m][r];
                const float a = hv / (1.f + __expf(-hv)) * uacc[m][r];
                act[(size_t)(p0 + rt) * NB + col] = f2bf(a);
            }
        }
    }
}

// ---------------- down GEMM: BM=128, BN=128, BK=64, 512 threads ----------------
// 8 waves as 2m x 4n; wave tile 64m x 32n. Same pipeline discipline as gateup.
// EXPERT=true : A = act rows (pair-major), epilogue atomicAdd(out, v*score)
// EXPERT=false: A = shared act, epilogue out = out*c0 + v*c1 (final combine)
template <bool EXPERT>
__global__ __launch_bounds__(512, 4)
void down_kernel(const unsigned short* __restrict__ act,
                 const float* __restrict__ Bd_all,
                 float* __restrict__ out,
                 const int* __restrict__ meta, const int* __restrict__ pair_token,
                 const float* __restrict__ pair_score, const float* __restrict__ coef,
                 const int KA)   // 512 or 1024; A row stride == KA; B row stride = DMODEL
{
    const int NT = KA / 64;   // 8 or 16 (even)
    __shared__ unsigned short Al[2][128][LDP];
    __shared__ unsigned short Bl[2][128][LDP];

    const int tid = threadIdx.x;
    int p0, mval;
    const float* Bd;
    if constexpr (EXPERT) {
        const int tt = blockIdx.y;
        if (tt >= meta[META_NT]) return;
        const int e = meta[META_TE + tt];
        p0 = meta[META_TP0 + tt];
        mval = meta[META_TM + tt];
        Bd = Bd_all + (size_t)e * KA * DMODEL;
    } else {
        p0 = blockIdx.y * 128;
        mval = 128;
        Bd = Bd_all;
    }
    const int n0 = blockIdx.x * 128;

    const int arow = tid >> 2;
    const int aoff = (tid & 3) * 16;
    int ar = p0 + arow;
    if constexpr (EXPERT) { if (ar > NPAIR - 1) ar = NPAIR - 1; }
    const unsigned short* asrc = act + (size_t)ar * KA + aoff;

    // B staging: col = tid&127, 16 k-values at bkb
    const int bcol = tid & 127;
    const int bkb = (tid >> 7) * 16;   // 4 k-groups x 16 k = 64
    const float* bsrc = Bd + (size_t)bkb * DMODEL + (n0 + bcol);

    uint4 areg0, areg1;
    float breg[16];

    auto load_regs = [&](int k0) {
        areg0 = *reinterpret_cast<const uint4*>(asrc + k0);
        areg1 = *reinterpret_cast<const uint4*>(asrc + k0 + 8);
#pragma unroll
        for (int j = 0; j < 16; ++j)
            breg[j] = bsrc[(size_t)(k0 + j) * DMODEL];
    };
    auto write_lds = [&](int buf) {
        *reinterpret_cast<uint4*>(&Al[buf][arow][aoff])     = areg0;
        *reinterpret_cast<uint4*>(&Al[buf][arow][aoff + 8]) = areg1;
        uint4 b0, b1;
        b0.x = pack2bf(breg[0],  breg[1]);  b0.y = pack2bf(breg[2],  breg[3]);
        b0.z = pack2bf(breg[4],  breg[5]);  b0.w = pack2bf(breg[6],  breg[7]);
        b1.x = pack2bf(breg[8],  breg[9]);  b1.y = pack2bf(breg[10], breg[11]);
        b1.z = pack2bf(breg[12], breg[13]); b1.w = pack2bf(breg[14], breg[15]);
        *reinterpret_cast<uint4*>(&Bl[buf][bcol][bkb])     = b0;
        *reinterpret_cast<uint4*>(&Bl[buf][bcol][bkb + 8]) = b1;
    };

    const int lane = tid & 63;
    const int wave = tid >> 6;
    const int wm = wave >> 2, wn = wave & 3;   // 2m x 4n
    const int fr = lane & 15, fq = lane >> 4;

    const f32x4 zero4 = {0.f, 0.f, 0.f, 0.f};
    f32x4 acc[4][2];
#pragma unroll
    for (int m = 0; m < 4; ++m)
#pragma unroll
        for (int n = 0; n < 2; ++n) acc[m][n] = zero4;

    auto compute = [&](int buf) {
#pragma unroll
        for (int kk = 0; kk < 2; ++kk) {
            const int ko = kk * 32 + fq * 8;
            s16x8 af[4], bf[2];
#pragma unroll
            for (int m = 0; m < 4; ++m)
                af[m] = *reinterpret_cast<const s16x8*>(&Al[buf][wm * 64 + m * 16 + fr][ko]);
#pragma unroll
            for (int n = 0; n < 2; ++n)
                bf[n] = *reinterpret_cast<const s16x8*>(&Bl[buf][wn * 32 + n * 16 + fr][ko]);
#pragma unroll
            for (int m = 0; m < 4; ++m)
#pragma unroll
                for (int n = 0; n < 2; ++n)
                    acc[m][n] = mfma16x16x32(af[m], bf[n], acc[m][n]);
        }
    };

    load_regs(0);
    write_lds(0);
    __syncthreads();
#pragma unroll 1
    for (int t = 0; t < NT; t += 2) {
        if (t + 1 < NT) load_regs((t + 1) * 64);
        compute(0);
        if (t + 1 < NT) write_lds(1);
        __syncthreads();
        if (t + 2 < NT) load_regs((t + 2) * 64);
        compute(1);
        if (t + 2 < NT) write_lds(0);
        __syncthreads();
    }

#pragma unroll
    for (int m = 0; m < 4; ++m)
#pragma unroll
        for (int n = 0; n < 2; ++n) {
            const int col = n0 + wn * 32 + n * 16 + fr;
#pragma unroll
            for (int r = 0; r < 4; ++r) {
                const int rt = wm * 64 + m * 16 + fq * 4 + r;
                if (rt < mval) {
                    if constexpr (EXPERT) {
                        const int p = p0 + rt;
                        const int t2 = pair_token[p];
                        const float s = pair_score[p];
                        atomicAdd(&out[(size_t)t2 * DMODEL + col], acc[m][n][r] * s);
                    } else {
                        const int row = p0 + rt;
                        const float c0 = coef[row * 2 + 0];
                        const float c1 = coef[row * 2 + 1];
                        const size_t idx = (size_t)row * DMODEL + col;
                        out[idx] = out[idx] * c0 + acc[m][n][r] * c1;
                    }
                }
            }
        }
}

// ---------------- launch ----------------
extern "C" void kernel_launch(void* const* d_in, const int* in_sizes, int n_in,
                              void* d_out, int out_size, void* d_ws, size_t ws_size,
                              hipStream_t stream)
{
    const float* x           = (const float*)d_in[0];
    const float* gate_w      = (const float*)d_in[1];
    const float* expert_bias = (const float*)d_in[2];
    const float* wg          = (const float*)d_in[3];
    const float* wu          = (const float*)d_in[4];
    const float* wd          = (const float*)d_in[5];
    const float* sg          = (const float*)d_in[6];
    const float* su          = (const float*)d_in[7];
    const float* sd          = (const float*)d_in[8];
    const float* coef_w      = (const float*)d_in[9];
    const float* coef_b      = (const float*)d_in[10];
    float* out = (float*)d_out;

    char* ws = (char*)d_ws;
    size_t off = 0;
    auto take = [&](size_t bytes) {
        char* p = ws + off;
        off = (off + bytes + 255) & ~(size_t)255;
        return p;
    };
    int*   inds     = (int*)  take((size_t)S_TOK * 4 * sizeof(int));
    float* scores   = (float*)take((size_t)S_TOK * 4 * sizeof(float));
    float* coefp    = (float*)take((size_t)S_TOK * 2 * sizeof(float));
    int*   meta     = (int*)  take((size_t)META_SIZE * sizeof(int));
    int*   pair_tok = (int*)  take((size_t)NPAIR * sizeof(int));
    float* pair_sc  = (float*)take((size_t)NPAIR * sizeof(float));
    unsigned short* xb    = (unsigned short*)take((size_t)S_TOK * DMODEL * 2);
    unsigned short* act   = (unsigned short*)take((size_t)NPAIR * HEXP * 2);
    unsigned short* shact = (unsigned short*)take((size_t)S_TOK * HSH * 2);
    (void)ws_size; (void)in_sizes; (void)n_in; (void)out_size;

    // out doubles as the expert-y accumulator; zero it each call
    hipMemsetAsync(d_out, 0, (size_t)S_TOK * DMODEL * sizeof(float), stream);

    router_kernel<<<S_TOK, 256, 0, stream>>>(x, gate_w, expert_bias, coef_w, coef_b,
                                             inds, scores, coefp);
    xcast_kernel<<<(S_TOK * DMODEL / 4) / 256, 256, 0, stream>>>(x, xb);
    group_kernel<<<1, 1024, 0, stream>>>(inds, scores, meta, pair_tok, pair_sc);

    // expert gate+up (+SwiGLU): 8 n-tiles x up-to-96 m-tiles (tile table)
    gateup_kernel<true><<<dim3(HEXP / 64, MAXTILES), 512, 0, stream>>>(
        xb, wg, wu, act, meta, pair_tok, HEXP);
    // shared gate+up: N=1024, M=2048
    gateup_kernel<false><<<dim3(HSH / 64, S_TOK / 128), 512, 0, stream>>>(
        xb, sg, su, shact, nullptr, nullptr, HSH);
    // expert down: N=2048 (BN=128), K=512; scaled atomic accumulate into out
    down_kernel<true><<<dim3(DMODEL / 128, MAXTILES), 512, 0, stream>>>(
        act, wd, out, meta, pair_tok, pair_sc, nullptr, HEXP);
    // shared down + final 2-way coef mix (reads accumulated expert y in-place)
    down_kernel<false><<<dim3(DMODEL / 128, S_TOK / 128), 512, 0, stream>>>(
        shact, sd, out, nullptr, nullptr, nullptr, coefp, HSH);
}